// Round 1
// baseline (350.234 us; speedup 1.0000x reference)
//
#include <hip/hip_runtime.h>

#define MARGIN 0.4f

__global__ __launch_bounds__(256) void triplet_loss_kernel(
    const float* __restrict__ anchor,
    const float* __restrict__ positive,
    const float* __restrict__ negatives,
    float* __restrict__ out, int N)
{
    const int lane = threadIdx.x & 63;
    const int waveInBlock = threadIdx.x >> 6;

    // ---- pos_sim = dot(anchor, positive) over D=128, once per wave ----
    // lane l covers elements l and l+64; full 64-lane butterfly reduce.
    float ps = anchor[lane] * positive[lane] + anchor[lane + 64] * positive[lane + 64];
    #pragma unroll
    for (int m = 1; m < 64; m <<= 1)
        ps += __shfl_xor(ps, m, 64);
    const float c = ps + MARGIN;   // constant added before subtracting neg_sim

    // ---- anchor fragment for the main loop ----
    // lanes 0..31 and 32..63 each cover a full 128-float row: col = (lane&31)*4
    const int col = (lane & 31) << 2;
    const float4 af = *reinterpret_cast<const float4*>(anchor + col);

    const int half = lane >> 5;              // which row of the pair this lane reads
    const long long nPairs = (long long)N >> 1;
    long long p = (long long)blockIdx.x * 4 + waveInBlock;
    const long long stride = (long long)gridDim.x * 4;

    float acc = 0.0f;
    for (; p < nPairs; p += stride) {
        const long long row = 2 * p + half;
        const float4 nf = *reinterpret_cast<const float4*>(negatives + row * 128 + col);
        float d = nf.x * af.x + nf.y * af.y + nf.z * af.z + nf.w * af.w;
        // reduce within each 32-lane half (xor masks < 32 keep halves separate)
        d += __shfl_xor(d, 1, 64);
        d += __shfl_xor(d, 2, 64);
        d += __shfl_xor(d, 4, 64);
        d += __shfl_xor(d, 8, 64);
        d += __shfl_xor(d, 16, 64);
        // after butterfly, all lanes of a half hold the row dot; count it once
        if ((lane & 31) == 0) {
            const float loss = c - d;
            acc += loss > 0.0f ? loss : 0.0f;
        }
    }

    // ---- odd-N tail (not hit for N=500000, kept for generality) ----
    if ((N & 1) && blockIdx.x == 0 && waveInBlock == 0) {
        const long long row = (long long)N - 1;
        if (half == 0) {
            const float4 nf = *reinterpret_cast<const float4*>(negatives + row * 128 + col);
            float d = nf.x * af.x + nf.y * af.y + nf.z * af.z + nf.w * af.w;
            d += __shfl_xor(d, 1, 64);
            d += __shfl_xor(d, 2, 64);
            d += __shfl_xor(d, 4, 64);
            d += __shfl_xor(d, 8, 64);
            d += __shfl_xor(d, 16, 64);
            if (lane == 0) {
                const float loss = c - d;
                acc += loss > 0.0f ? loss : 0.0f;
            }
        }
    }

    // ---- block reduction: wave butterfly -> LDS -> one atomic per block ----
    #pragma unroll
    for (int m = 1; m < 64; m <<= 1)
        acc += __shfl_xor(acc, m, 64);

    __shared__ float waveSums[4];
    if (lane == 0) waveSums[waveInBlock] = acc;
    __syncthreads();
    if (threadIdx.x == 0) {
        const float s = waveSums[0] + waveSums[1] + waveSums[2] + waveSums[3];
        atomicAdd(out, s * (1.0f / (float)N));
    }
}

extern "C" void kernel_launch(void* const* d_in, const int* in_sizes, int n_in,
                              void* d_out, int out_size, void* d_ws, size_t ws_size,
                              hipStream_t stream) {
    const float* anchor    = (const float*)d_in[0];
    const float* positive  = (const float*)d_in[1];
    const float* negatives = (const float*)d_in[2];
    float* out = (float*)d_out;

    const int D = 128;
    const int N = in_sizes[2] / D;   // 500000

    // d_out is re-poisoned to 0xAA before every launch; zero it for the atomics.
    hipMemsetAsync(out, 0, sizeof(float), stream);

    triplet_loss_kernel<<<2048, 256, 0, stream>>>(anchor, positive, negatives, out, N);
}